// Round 4
// baseline (2468.121 us; speedup 1.0000x reference)
//
#include <hip/hip_runtime.h>

// Problem constants
#define BB 4
#define SS 4096
#define DD 2048
#define NHEAD 16
#define HDIM 128
#define MM (BB * SS)   // 16384 rows

typedef _Float16 f16;
typedef __attribute__((ext_vector_type(8))) _Float16 half8;
typedef __attribute__((ext_vector_type(4))) _Float16 half4;
typedef __attribute__((ext_vector_type(4))) float floatx4;

typedef __attribute__((address_space(3))) char lds_char;
typedef const __attribute__((address_space(1))) char glb_char;

__device__ __forceinline__ void async_copy16(const void* g, void* l) {
    // global -> LDS direct copy, 16B per lane; LDS dest = wave-uniform base + lane*16
    __builtin_amdgcn_global_load_lds((glb_char*)g, (lds_char*)l, 16, 0, 0);
}

// ---------------- cast fp32 -> fp16 (vectorized) ----------------
__global__ __launch_bounds__(256) void cast_f32_f16_kernel(
    const float* __restrict__ src, f16* __restrict__ dst, int n4) {
    int i = blockIdx.x * blockDim.x + threadIdx.x;
    if (i < n4) {
        float4 v = ((const float4*)src)[i];
        half4 h;
        h[0] = (f16)v.x; h[1] = (f16)v.y; h[2] = (f16)v.z; h[3] = (f16)v.w;
        ((half4*)dst)[i] = h;
    }
}

// ---------------- transpose + cast: dst[e][d] = src[d][e] ----------------
__global__ __launch_bounds__(256) void transpose_cast_kernel(
    const float* __restrict__ src, f16* __restrict__ dst, int dim) {
    __shared__ float tile[32][33];   // +1 pad: conflict-free transpose
    int tx = threadIdx.x & 31, ty = threadIdx.x >> 5;  // 32 x 8
    int bx = blockIdx.x * 32, by = blockIdx.y * 32;
#pragma unroll
    for (int r = 0; r < 4; ++r)
        tile[ty + 8 * r][tx] = src[(size_t)(by + ty + 8 * r) * dim + bx + tx];
    __syncthreads();
#pragma unroll
    for (int r = 0; r < 4; ++r)
        dst[(size_t)(bx + ty + 8 * r) * dim + by + tx] = (f16)tile[tx][ty + 8 * r];
}

// ---------------- fp16 MFMA GEMM: C[M,N] = A[M,K] @ Bt[N,K]^T ----------------
// 128x128 tile, BK=32, 256 threads = 4 waves in 2x2, each wave 64x64 (4x4 frags of 16x16x32)
// MODE 0: out fp16 with fp32 bias (input projection -> x buffer)
// MODE 1: out fp32, no bias (output projection -> d_out)
template <int MODE>
__global__ __launch_bounds__(256) void gemm_f16_kernel(
    const f16* __restrict__ A, const f16* __restrict__ Bt,
    const float* __restrict__ bias, f16* __restrict__ outH,
    float* __restrict__ outF, int M, int N, int K) {
    __shared__ __align__(16) char smem[16384];   // As 8KB | Bs 8KB
    f16* As = (f16*)smem;
    f16* Bs = (f16*)(smem + 8192);

    const int tid = threadIdx.x;
    const int lane = tid & 63;
    const int wave = tid >> 6;
    const int wm = wave >> 1, wn = wave & 1;
    const int lm = lane & 15, quad = lane >> 4;
    const int m0 = blockIdx.y * 128, n0 = blockIdx.x * 128;

    floatx4 acc[4][4];
#pragma unroll
    for (int i = 0; i < 4; ++i)
#pragma unroll
        for (int j = 0; j < 4; ++j)
#pragma unroll
            for (int r = 0; r < 4; ++r) acc[i][j][r] = 0.f;

    const int srow = tid >> 2;
    const int skk = (tid & 3) * 8;
    const int wbase = (tid >> 6) * 1024;  // wave-uniform LDS byte base
    const f16* Ag = A + (size_t)(m0 + srow) * K + skk;
    const f16* Bg = Bt + (size_t)(n0 + srow) * K + skk;

    for (int kb = 0; kb < K; kb += 32) {
        async_copy16(Ag + kb, smem + 0 + wbase);
        async_copy16(Ag + (size_t)64 * K + kb, smem + 4096 + wbase);
        async_copy16(Bg + kb, smem + 8192 + wbase);
        async_copy16(Bg + (size_t)64 * K + kb, smem + 12288 + wbase);
        asm volatile("s_waitcnt vmcnt(0)" ::: "memory");
        __syncthreads();

        half8 af[4], bf[4];
#pragma unroll
        for (int i = 0; i < 4; ++i)
            af[i] = *(const half8*)(As + (wm * 64 + i * 16 + lm) * 32 + quad * 8);
#pragma unroll
        for (int j = 0; j < 4; ++j)
            bf[j] = *(const half8*)(Bs + (wn * 64 + j * 16 + lm) * 32 + quad * 8);
#pragma unroll
        for (int i = 0; i < 4; ++i)
#pragma unroll
            for (int j = 0; j < 4; ++j)
                acc[i][j] = __builtin_amdgcn_mfma_f32_16x16x32_f16(af[i], bf[j], acc[i][j], 0, 0, 0);
        __syncthreads();
    }

#pragma unroll
    for (int j = 0; j < 4; ++j) {
        int col = n0 + wn * 64 + j * 16 + lm;
        float bj = (MODE == 0) ? bias[col] : 0.f;
#pragma unroll
        for (int i = 0; i < 4; ++i) {
            int row0 = m0 + wm * 64 + i * 16 + quad * 4;
#pragma unroll
            for (int r = 0; r < 4; ++r) {
                float v = acc[i][j][r] + bj;
                if (MODE == 0) outH[(size_t)(row0 + r) * N + col] = (f16)v;
                else           outF[(size_t)(row0 + r) * N + col] = v;
            }
        }
    }
}

// ---------------- sequential scan via MFMA: one workgroup per head n ----------------
// C(out-dims x batch) = W^T(A, regs) * h(B, LDS).  4 waves, wave w owns out-dims
// [32w,32w+32) as 2 rowtiles of 16.  Batches are MFMA columns (4 of 16 used; cols
// 4-15 duplicate batch col&3 -> finite garbage, masked on write).
// Per step/wave: 4 ds_read_b128 (h) + 8 MFMA (two 2-deep chains/acc) + tanh +
// 2 masked b64 h writes; x comes from REGISTERS (global prefetch, depth 2);
// y goes DIRECT to global (scatter b64, 4x32B contiguous segments/instr).
// ONE raw s_barrier + lgkmcnt(0) per step; h double-buffered in LDS (2.5KB total).

// h LDS byte offset: batch b (0..3), element k (0..127).  Padded-linear (stride 320B):
// b128 reads: chunk index (b*20 + quad) mod 8 -> 2-way bank aliasing = free on CDNA4.
__device__ __forceinline__ int h_off(int b, int k) {
    return b * 320 + k * 2;
}

__global__ __launch_bounds__(256) void scan_kernel(
    const f16* __restrict__ xb, const float* __restrict__ state_weight,
    const float* __restrict__ input_state, f16* __restrict__ yb) {
    const int n = blockIdx.x;          // head
    const int tid = threadIdx.x;
    const int lane = tid & 63;
    const int w = tid >> 6;
    const int lm = lane & 15;          // C col (batch for lm<4)
    const int quad = lane >> 4;
    const int bb = lane & 3;           // clamped batch (== lm for active lanes)

    __shared__ __align__(16) char hsb[2][4 * 320];      // 2.5 KB h ping-pong

    // ---- W A-frags: wfrag[rt][kt][j] = W[n][h = kt*32+quad*8+j][p = (w*2+rt)*16+lm]
    half8 wfrag[2][4];
    {
        const float* Wn = state_weight + (size_t)n * HDIM * HDIM;
#pragma unroll
        for (int rt = 0; rt < 2; ++rt) {
            const int row = (w * 2 + rt) * 16 + lm;
#pragma unroll
            for (int kt = 0; kt < 4; ++kt) {
                half8 f;
#pragma unroll
                for (int j = 0; j < 8; ++j)
                    f[j] = (f16)Wn[(size_t)(kt * 32 + quad * 8 + j) * HDIM + row];
                wfrag[rt][kt] = f;
            }
        }
    }

    // ---- init h0
    for (int idx = tid; idx < 512; idx += 256) {
        int b = idx >> 7, k = idx & 127;
        *(f16*)&hsb[0][h_off(b, k)] =
            (f16)input_state[((size_t)b * NHEAD + n) * HDIM + k];
    }
    __syncthreads();

    const int kp0 = w * 32 + quad * 4;    // out-dim base, rowtile 0
    const int kp1 = kp0 + 16;             // rowtile 1 (= kp0 + 16)

    // per-lane global x/y pointers: element offset (bb*SS + t)*DD + n*128 + kp0
    const f16* xp0 = xb + (size_t)n * HDIM + (size_t)bb * SS * DD + kp0;
    f16* yp       = yb + (size_t)n * HDIM + (size_t)bb * SS * DD + kp0;

    // ---- register x prefetch, depth 2 (static names; no runtime-indexed arrays)
    half4 pa0 = *(const half4*)(xp0);
    half4 pc0 = *(const half4*)(xp0 + 16);
    half4 pa1 = *(const half4*)(xp0 + DD);
    half4 pc1 = *(const half4*)(xp0 + DD + 16);
    const f16* xpre = xp0 + 2 * DD;       // load address for t+2

    const bool wlane = (lm < 4);

#pragma unroll 1
    for (int t = 0; t < SS; t += 2) {
        // clamp prefetch address at the tail (re-reads row 0; values unused)
        const f16* xq = (t + 2 < SS) ? xpre : xp0;

        // ================= step t (even): read hsb[0], write hsb[1] =================
        {
            half4 xa = pa0, xc = pc0;
            pa0 = *(const half4*)(xq);
            pc0 = *(const half4*)(xq + 16);

            const char* hr = hsb[0];
            char* hw2 = hsb[1];
            half8 hf0 = *(const half8*)(hr + h_off(bb, 0 * 32 + quad * 8));
            half8 hf1 = *(const half8*)(hr + h_off(bb, 1 * 32 + quad * 8));
            half8 hf2 = *(const half8*)(hr + h_off(bb, 2 * 32 + quad * 8));
            half8 hf3 = *(const half8*)(hr + h_off(bb, 3 * 32 + quad * 8));

            floatx4 c0a, c0b, c1a, c1b;
#pragma unroll
            for (int r = 0; r < 4; ++r) {
                c0a[r] = (float)xa[r]; c1a[r] = (float)xc[r];
                c0b[r] = 0.f;          c1b[r] = 0.f;
            }
            c0a = __builtin_amdgcn_mfma_f32_16x16x32_f16(wfrag[0][0], hf0, c0a, 0, 0, 0);
            c0b = __builtin_amdgcn_mfma_f32_16x16x32_f16(wfrag[0][2], hf2, c0b, 0, 0, 0);
            c1a = __builtin_amdgcn_mfma_f32_16x16x32_f16(wfrag[1][0], hf0, c1a, 0, 0, 0);
            c1b = __builtin_amdgcn_mfma_f32_16x16x32_f16(wfrag[1][2], hf2, c1b, 0, 0, 0);
            c0a = __builtin_amdgcn_mfma_f32_16x16x32_f16(wfrag[0][1], hf1, c0a, 0, 0, 0);
            c0b = __builtin_amdgcn_mfma_f32_16x16x32_f16(wfrag[0][3], hf3, c0b, 0, 0, 0);
            c1a = __builtin_amdgcn_mfma_f32_16x16x32_f16(wfrag[1][1], hf1, c1a, 0, 0, 0);
            c1b = __builtin_amdgcn_mfma_f32_16x16x32_f16(wfrag[1][3], hf3, c1b, 0, 0, 0);

            half4 h0, h1;
#pragma unroll
            for (int r = 0; r < 4; ++r) {
                float v = c0a[r] + c0b[r];
                float ex = __expf(2.f * v);
                h0[r] = (f16)(1.f - 2.f * __builtin_amdgcn_rcpf(ex + 1.f));
            }
#pragma unroll
            for (int r = 0; r < 4; ++r) {
                float v = c1a[r] + c1b[r];
                float ex = __expf(2.f * v);
                h1[r] = (f16)(1.f - 2.f * __builtin_amdgcn_rcpf(ex + 1.f));
            }

            if (wlane) {   // real batch columns only (bb == lm here)
                *(half4*)(hw2 + h_off(lm, kp0)) = h0;
                *(half4*)(hw2 + h_off(lm, kp1)) = h1;
                *(half4*)yp = h0;
                *(half4*)(yp + 16) = h1;
            }
            asm volatile("s_waitcnt lgkmcnt(0)" ::: "memory");
            __builtin_amdgcn_s_barrier();       // raw: no vmcnt drain
        }
        yp += DD;

        // ================= step t+1 (odd): read hsb[1], write hsb[0] =================
        {
            half4 xa = pa1, xc = pc1;
            pa1 = *(const half4*)(xq + DD);
            pc1 = *(const half4*)(xq + DD + 16);

            const char* hr = hsb[1];
            char* hw2 = hsb[0];
            half8 hf0 = *(const half8*)(hr + h_off(bb, 0 * 32 + quad * 8));
            half8 hf1 = *(const half8*)(hr + h_off(bb, 1 * 32 + quad * 8));
            half8 hf2 = *(const half8*)(hr + h_off(bb, 2 * 32 + quad * 8));
            half8 hf3 = *(const half8*)(hr + h_off(bb, 3 * 32 + quad * 8));

            floatx4 c0a, c0b, c1a, c1b;
#pragma unroll
            for (int r = 0; r < 4; ++r) {
                c0a[r] = (float)xa[r]; c1a[r] = (float)xc[r];
                c0b[r] = 0.f;          c1b[r] = 0.f;
            }
            c0a = __builtin_amdgcn_mfma_f32_16x16x32_f16(wfrag[0][0], hf0, c0a, 0, 0, 0);
            c0b = __builtin_amdgcn_mfma_f32_16x16x32_f16(wfrag[0][2], hf2, c0b, 0, 0, 0);
            c1a = __builtin_amdgcn_mfma_f32_16x16x32_f16(wfrag[1][0], hf0, c1a, 0, 0, 0);
            c1b = __builtin_amdgcn_mfma_f32_16x16x32_f16(wfrag[1][2], hf2, c1b, 0, 0, 0);
            c0a = __builtin_amdgcn_mfma_f32_16x16x32_f16(wfrag[0][1], hf1, c0a, 0, 0, 0);
            c0b = __builtin_amdgcn_mfma_f32_16x16x32_f16(wfrag[0][3], hf3, c0b, 0, 0, 0);
            c1a = __builtin_amdgcn_mfma_f32_16x16x32_f16(wfrag[1][1], hf1, c1a, 0, 0, 0);
            c1b = __builtin_amdgcn_mfma_f32_16x16x32_f16(wfrag[1][3], hf3, c1b, 0, 0, 0);

            half4 h0, h1;
#pragma unroll
            for (int r = 0; r < 4; ++r) {
                float v = c0a[r] + c0b[r];
                float ex = __expf(2.f * v);
                h0[r] = (f16)(1.f - 2.f * __builtin_amdgcn_rcpf(ex + 1.f));
            }
#pragma unroll
            for (int r = 0; r < 4; ++r) {
                float v = c1a[r] + c1b[r];
                float ex = __expf(2.f * v);
                h1[r] = (f16)(1.f - 2.f * __builtin_amdgcn_rcpf(ex + 1.f));
            }

            if (wlane) {
                *(half4*)(hw2 + h_off(lm, kp0)) = h0;
                *(half4*)(hw2 + h_off(lm, kp1)) = h1;
                *(half4*)yp = h0;
                *(half4*)(yp + 16) = h1;
            }
            asm volatile("s_waitcnt lgkmcnt(0)" ::: "memory");
            __builtin_amdgcn_s_barrier();
        }
        yp += DD;
        xpre += 2 * DD;
    }
}

// ---------------- launch ----------------
extern "C" void kernel_launch(void* const* d_in, const int* in_sizes, int n_in,
                              void* d_out, int out_size, void* d_ws, size_t ws_size,
                              hipStream_t stream) {
    const float* input       = (const float*)d_in[0];
    const float* input_state = (const float*)d_in[1];
    const float* w_in        = (const float*)d_in[2];
    const float* b_in        = (const float*)d_in[3];
    const float* state_w     = (const float*)d_in[4];
    const float* w_out       = (const float*)d_in[5];
    float* out = (float*)d_out;

    // workspace layout (144 MB total):
    //   [0, 64MB)      Ab  : input cast to f16   (reused as yb after GEMM1)
    //   [64, 72MB)     W1b : w_in^T  f16
    //   [72, 80MB)     W2b : w_out^T f16
    //   [80, 144MB)    xb  : projected input, f16
    char* ws = (char*)d_ws;
    f16* Ab  = (f16*)ws;
    f16* W1b = (f16*)(ws + 67108864);
    f16* W2b = (f16*)(ws + 75497472);
    f16* xb  = (f16*)(ws + 83886080);
    f16* yb  = Ab;  // alias: Ab is dead after GEMM1

    cast_f32_f16_kernel<<<(MM * DD / 4 + 255) / 256, 256, 0, stream>>>(input, Ab, MM * DD / 4);

    dim3 tg(DD / 32, DD / 32);
    transpose_cast_kernel<<<tg, 256, 0, stream>>>(w_in, W1b, DD);
    transpose_cast_kernel<<<tg, 256, 0, stream>>>(w_out, W2b, DD);

    dim3 gg(DD / 128, MM / 128);
    gemm_f16_kernel<0><<<gg, 256, 0, stream>>>(Ab, W1b, b_in, xb, nullptr, MM, DD, DD);

    scan_kernel<<<NHEAD, 256, 0, stream>>>(xb, state_w, input_state, yb);

    gemm_f16_kernel<1><<<gg, 256, 0, stream>>>(yb, W2b, nullptr, nullptr, out, MM, DD, DD);
}

// Round 5
// 1878.090 us; speedup vs baseline: 1.3142x; 1.3142x over previous
//
#include <hip/hip_runtime.h>

// Problem constants
#define BB 4
#define SS 4096
#define DD 2048
#define NHEAD 16
#define HDIM 128
#define MM (BB * SS)   // 16384 rows

typedef _Float16 f16;
typedef __attribute__((ext_vector_type(8))) _Float16 half8;
typedef __attribute__((ext_vector_type(4))) _Float16 half4;
typedef __attribute__((ext_vector_type(4))) float floatx4;

typedef __attribute__((address_space(3))) char lds_char;
typedef const __attribute__((address_space(1))) char glb_char;

__device__ __forceinline__ void async_copy16(const void* g, void* l) {
    __builtin_amdgcn_global_load_lds((glb_char*)g, (lds_char*)l, 16, 0, 0);
}

// ---------------- cast fp32 -> fp16 (vectorized) ----------------
__global__ __launch_bounds__(256) void cast_f32_f16_kernel(
    const float* __restrict__ src, f16* __restrict__ dst, int n4) {
    int i = blockIdx.x * blockDim.x + threadIdx.x;
    if (i < n4) {
        float4 v = ((const float4*)src)[i];
        half4 h;
        h[0] = (f16)v.x; h[1] = (f16)v.y; h[2] = (f16)v.z; h[3] = (f16)v.w;
        ((half4*)dst)[i] = h;
    }
}

// ---------------- transpose + cast: dst[e][d] = src[d][e] ----------------
__global__ __launch_bounds__(256) void transpose_cast_kernel(
    const float* __restrict__ src, f16* __restrict__ dst, int dim) {
    __shared__ float tile[32][33];
    int tx = threadIdx.x & 31, ty = threadIdx.x >> 5;
    int bx = blockIdx.x * 32, by = blockIdx.y * 32;
#pragma unroll
    for (int r = 0; r < 4; ++r)
        tile[ty + 8 * r][tx] = src[(size_t)(by + ty + 8 * r) * dim + bx + tx];
    __syncthreads();
#pragma unroll
    for (int r = 0; r < 4; ++r)
        dst[(size_t)(bx + ty + 8 * r) * dim + by + tx] = (f16)tile[tx][ty + 8 * r];
}

// ---------------- fp16 MFMA GEMM (unchanged) ----------------
template <int MODE>
__global__ __launch_bounds__(256) void gemm_f16_kernel(
    const f16* __restrict__ A, const f16* __restrict__ Bt,
    const float* __restrict__ bias, f16* __restrict__ outH,
    float* __restrict__ outF, int M, int N, int K) {
    __shared__ __align__(16) char smem[16384];
    f16* As = (f16*)smem;
    f16* Bs = (f16*)(smem + 8192);

    const int tid = threadIdx.x;
    const int lane = tid & 63;
    const int wave = tid >> 6;
    const int wm = wave >> 1, wn = wave & 1;
    const int lm = lane & 15, quad = lane >> 4;
    const int m0 = blockIdx.y * 128, n0 = blockIdx.x * 128;

    floatx4 acc[4][4];
#pragma unroll
    for (int i = 0; i < 4; ++i)
#pragma unroll
        for (int j = 0; j < 4; ++j)
#pragma unroll
            for (int r = 0; r < 4; ++r) acc[i][j][r] = 0.f;

    const int srow = tid >> 2;
    const int skk = (tid & 3) * 8;
    const int wbase = (tid >> 6) * 1024;
    const f16* Ag = A + (size_t)(m0 + srow) * K + skk;
    const f16* Bg = Bt + (size_t)(n0 + srow) * K + skk;

    for (int kb = 0; kb < K; kb += 32) {
        async_copy16(Ag + kb, smem + 0 + wbase);
        async_copy16(Ag + (size_t)64 * K + kb, smem + 4096 + wbase);
        async_copy16(Bg + kb, smem + 8192 + wbase);
        async_copy16(Bg + (size_t)64 * K + kb, smem + 12288 + wbase);
        asm volatile("s_waitcnt vmcnt(0)" ::: "memory");
        __syncthreads();

        half8 af[4], bf[4];
#pragma unroll
        for (int i = 0; i < 4; ++i)
            af[i] = *(const half8*)(As + (wm * 64 + i * 16 + lm) * 32 + quad * 8);
#pragma unroll
        for (int j = 0; j < 4; ++j)
            bf[j] = *(const half8*)(Bs + (wn * 64 + j * 16 + lm) * 32 + quad * 8);
#pragma unroll
        for (int i = 0; i < 4; ++i)
#pragma unroll
            for (int j = 0; j < 4; ++j)
                acc[i][j] = __builtin_amdgcn_mfma_f32_16x16x32_f16(af[i], bf[j], acc[i][j], 0, 0, 0);
        __syncthreads();
    }

#pragma unroll
    for (int j = 0; j < 4; ++j) {
        int col = n0 + wn * 64 + j * 16 + lm;
        float bj = (MODE == 0) ? bias[col] : 0.f;
#pragma unroll
        for (int i = 0; i < 4; ++i) {
            int row0 = m0 + wm * 64 + i * 16 + quad * 4;
#pragma unroll
            for (int r = 0; r < 4; ++r) {
                float v = acc[i][j][r] + bj;
                if (MODE == 0) outH[(size_t)(row0 + r) * N + col] = (f16)v;
                else           outF[(size_t)(row0 + r) * N + col] = v;
            }
        }
    }
}

// ---------------- sequential scan via MFMA: one workgroup per head n ----------------
// 8 waves (512 thr, 2 waves/SIMD for latency overlap), wave w owns out-dim rowtile
// [16w, 16w+16).  Batches are MFMA columns (4 of 16 real; dup cols finite garbage).
// Per step/wave: 4 ds_read_b128 (h) + 4 MFMA (two 2-deep chains) + 4-value tanh +
// 1 masked b64 h write; x from registers (4-step-deep prefetch, cvt'd to f32 off
// the critical path, fed directly as MFMA C-in); y direct to global (never waited).
// ONE raw s_barrier + lgkmcnt(0) per step; h double-buffered in LDS (2.5 KB).

// h LDS byte offset: padded-linear (stride 320B): b128 reads 2-way = free; b64
// writes 2-way = free.  Bijective.
__device__ __forceinline__ int h_off(int b, int k) {
    return b * 320 + k * 2;
}

__global__ __launch_bounds__(512) void scan_kernel(
    const f16* __restrict__ xb, const float* __restrict__ state_weight,
    const float* __restrict__ input_state, f16* __restrict__ yb) {
    const int n = blockIdx.x;          // head
    const int tid = threadIdx.x;
    const int lane = tid & 63;
    const int w = tid >> 6;            // wave = rowtile, 0..7
    const int lm = lane & 15;          // C col (batch for lm<4)
    const int quad = lane >> 4;
    const int bb = lane & 3;           // clamped batch

    __shared__ __align__(16) char hsb[2][1280];   // h ping-pong, 4 batches x 320B

    // W A-frags: wfrag[kt][j] = W[n][h = kt*32+quad*8+j][p = w*16+lm]
    half8 wfrag[4];
    {
        const float* Wn = state_weight + (size_t)n * HDIM * HDIM;
        const int row = w * 16 + lm;
#pragma unroll
        for (int kt = 0; kt < 4; ++kt) {
            half8 f;
#pragma unroll
            for (int j = 0; j < 8; ++j)
                f[j] = (f16)Wn[(size_t)(kt * 32 + quad * 8 + j) * HDIM + row];
            wfrag[kt] = f;
        }
    }

    // init h0 (512 threads cover 4 x 128 exactly)
    {
        int b = tid >> 7, k = tid & 127;
        *(f16*)&hsb[0][h_off(b, k)] =
            (f16)input_state[((size_t)b * NHEAD + n) * HDIM + k];
    }
    __syncthreads();

    const int kp = w * 16 + quad * 4;  // out-dim base for this lane
    const f16* xp0 = xb + (size_t)n * HDIM + (size_t)bb * SS * DD + kp;
    f16* yp       = yb + (size_t)n * HDIM + (size_t)bb * SS * DD + kp;

    // ---- x prefetch: depth 4 steps, static names.  ph* loaded 1 body (4 steps)
    // ahead; cvt'd to pf* at body top (load is ~4 steps old there = off-path).
    half4 ph0 = *(const half4*)(xp0 + 0 * DD);
    half4 ph1 = *(const half4*)(xp0 + 1 * DD);
    half4 ph2 = *(const half4*)(xp0 + 2 * DD);
    half4 ph3 = *(const half4*)(xp0 + 3 * DD);
    const f16* xptr = xp0 + 4 * DD;    // next load base (x[t+4])

    const bool wlane = (lm < 4);

#pragma unroll 1
    for (int t = 0; t < SS; t += 4) {
        // convert this body's 4 x-vectors to f32 (loads 4 steps old -> no stall)
        floatx4 pf0, pf1, pf2, pf3;
#pragma unroll
        for (int r = 0; r < 4; ++r) {
            pf0[r] = (float)ph0[r]; pf1[r] = (float)ph1[r];
            pf2[r] = (float)ph2[r]; pf3[r] = (float)ph3[r];
        }
        // clamped reload addresses (tail re-reads row 0; values unused)
        const f16* xq0 = (t + 4 < SS) ? (xptr + 0 * DD) : xp0;
        const f16* xq1 = (t + 5 < SS) ? (xptr + 1 * DD) : xp0;
        const f16* xq2 = (t + 6 < SS) ? (xptr + 2 * DD) : xp0;
        const f16* xq3 = (t + 7 < SS) ? (xptr + 3 * DD) : xp0;

#define SCAN_STEP(PF, PH, XQ, PR)                                              \
        {                                                                      \
            PH = *(const half4*)(XQ);  /* reload: consumed next body */        \
            const char* hr = hsb[PR];                                          \
            char* hw = hsb[PR ^ 1];                                            \
            half8 hf0 = *(const half8*)(hr + h_off(bb, 0 + quad * 8));         \
            half8 hf1 = *(const half8*)(hr + h_off(bb, 32 + quad * 8));        \
            half8 hf2 = *(const half8*)(hr + h_off(bb, 64 + quad * 8));        \
            half8 hf3 = *(const half8*)(hr + h_off(bb, 96 + quad * 8));        \
            floatx4 ca = PF;                                                   \
            floatx4 cb;                                                        \
            cb[0] = 0.f; cb[1] = 0.f; cb[2] = 0.f; cb[3] = 0.f;                \
            ca = __builtin_amdgcn_mfma_f32_16x16x32_f16(wfrag[0], hf0, ca, 0, 0, 0); \
            cb = __builtin_amdgcn_mfma_f32_16x16x32_f16(wfrag[2], hf2, cb, 0, 0, 0); \
            ca = __builtin_amdgcn_mfma_f32_16x16x32_f16(wfrag[1], hf1, ca, 0, 0, 0); \
            cb = __builtin_amdgcn_mfma_f32_16x16x32_f16(wfrag[3], hf3, cb, 0, 0, 0); \
            half4 hv;                                                          \
            _Pragma("unroll")                                                  \
            for (int r = 0; r < 4; ++r) {                                      \
                float v = ca[r] + cb[r];                                       \
                float ex = __expf(2.f * v);                                    \
                hv[r] = (f16)(1.f - 2.f * __builtin_amdgcn_rcpf(ex + 1.f));    \
            }                                                                  \
            if (wlane) {                                                       \
                *(half4*)(hw + h_off(lm, kp)) = hv;                            \
                *(half4*)yp = hv;                                              \
            }                                                                  \
            asm volatile("s_waitcnt lgkmcnt(0)" ::: "memory");                 \
            __builtin_amdgcn_s_barrier();                                      \
            yp += DD;                                                          \
        }

        SCAN_STEP(pf0, ph0, xq0, 0)
        SCAN_STEP(pf1, ph1, xq1, 1)
        SCAN_STEP(pf2, ph2, xq2, 0)
        SCAN_STEP(pf3, ph3, xq3, 1)
#undef SCAN_STEP

        xptr += 4 * DD;
    }
}

// ---------------- launch ----------------
extern "C" void kernel_launch(void* const* d_in, const int* in_sizes, int n_in,
                              void* d_out, int out_size, void* d_ws, size_t ws_size,
                              hipStream_t stream) {
    const float* input       = (const float*)d_in[0];
    const float* input_state = (const float*)d_in[1];
    const float* w_in        = (const float*)d_in[2];
    const float* b_in        = (const float*)d_in[3];
    const float* state_w     = (const float*)d_in[4];
    const float* w_out       = (const float*)d_in[5];
    float* out = (float*)d_out;

    // workspace layout (144 MB total):
    //   [0, 64MB)      Ab  : input cast to f16   (reused as yb after GEMM1)
    //   [64, 72MB)     W1b : w_in^T  f16
    //   [72, 80MB)     W2b : w_out^T f16
    //   [80, 144MB)    xb  : projected input, f16
    char* ws = (char*)d_ws;
    f16* Ab  = (f16*)ws;
    f16* W1b = (f16*)(ws + 67108864);
    f16* W2b = (f16*)(ws + 75497472);
    f16* xb  = (f16*)(ws + 83886080);
    f16* yb  = Ab;  // alias: Ab is dead after GEMM1

    cast_f32_f16_kernel<<<(MM * DD / 4 + 255) / 256, 256, 0, stream>>>(input, Ab, MM * DD / 4);

    dim3 tg(DD / 32, DD / 32);
    transpose_cast_kernel<<<tg, 256, 0, stream>>>(w_in, W1b, DD);
    transpose_cast_kernel<<<tg, 256, 0, stream>>>(w_out, W2b, DD);

    dim3 gg(DD / 128, MM / 128);
    gemm_f16_kernel<0><<<gg, 256, 0, stream>>>(Ab, W1b, b_in, xb, nullptr, MM, DD, DD);

    scan_kernel<<<NHEAD, 512, 0, stream>>>(xb, state_w, input_state, yb);

    gemm_f16_kernel<1><<<gg, 256, 0, stream>>>(yb, W2b, nullptr, nullptr, out, MM, DD, DD);
}